// Round 1
// baseline (65.417 us; speedup 1.0000x reference)
//
#include <hip/hip_runtime.h>
#include <hip/hip_bf16.h>
#include <math.h>

// Problem constants (hardcoded per reference):
//   x_batch [32,128] f32, mu_c [10,128] f32, U [128,512] f32, V [128,512] f32
//   fac1 = x@U [32,512]; fac2 = mu@V [10,512]; h = fac1@fac2^T [32,10]
//   out = log_softmax(h, axis=-1)  -> 320 f32
#define BB 32
#define DD 128
#define KK 512
#define CC 10
#define KSPLIT 4
#define KCH (KK / KSPLIT)   // 128 threads per block in kernel A

// Kernel A: fac[r][k] for r in [0,42): r<32 -> x row r vs U; else mu row r-32 vs V.
// One thread per output element; row operand is block-uniform -> scalar loads.
__global__ __launch_bounds__(KCH) void fac_kernel(
    const float* __restrict__ x, const float* __restrict__ mu,
    const float* __restrict__ U, const float* __restrict__ V,
    float* __restrict__ fac)
{
    const int r  = blockIdx.x;            // 0..41
    const int ks = blockIdx.y;            // 0..KSPLIT-1
    const int k  = ks * KCH + threadIdx.x;

    const float* __restrict__ row = (r < BB) ? (x + r * DD) : (mu + (r - BB) * DD);
    const float* __restrict__ W   = (r < BB) ? U : V;

    float acc = 0.0f;
    #pragma unroll 16
    for (int d = 0; d < DD; ++d) {
        acc = fmaf(row[d], W[d * KK + k], acc);
    }
    fac[r * KK + k] = acc;
}

// Kernel B: one block (1 wave, 64 lanes) per batch row b.
// Each lane owns 8 consecutive k of fac1 row b; dot with each fac2 row c,
// butterfly-reduce across the wave, then log-softmax over the 10 values.
__global__ __launch_bounds__(64) void h_softmax_kernel(
    const float* __restrict__ fac, float* __restrict__ out)
{
    const int b    = blockIdx.x;      // 0..31
    const int lane = threadIdx.x;     // 0..63

    const float* __restrict__ f1 = fac + b * KK;
    const float* __restrict__ f2 = fac + BB * KK;   // fac2 base [10][512]

    const float4* f1v = (const float4*)(f1 + lane * 8);
    const float4 p0 = f1v[0];
    const float4 p1 = f1v[1];

    float hrow[CC];
    #pragma unroll
    for (int c = 0; c < CC; ++c) {
        const float4* f2v = (const float4*)(f2 + c * KK + lane * 8);
        const float4 q0 = f2v[0];
        const float4 q1 = f2v[1];
        float s = p0.x * q0.x + p0.y * q0.y + p0.z * q0.z + p0.w * q0.w
                + p1.x * q1.x + p1.y * q1.y + p1.z * q1.z + p1.w * q1.w;
        // Butterfly reduction over 64 lanes: every lane ends with the full sum.
        #pragma unroll
        for (int off = 32; off > 0; off >>= 1) {
            s += __shfl_xor(s, off);
        }
        hrow[c] = s;
    }

    // log_softmax over the 10-vector (redundantly computed by every lane).
    float mx = hrow[0];
    #pragma unroll
    for (int c = 1; c < CC; ++c) mx = fmaxf(mx, hrow[c]);
    float sum = 0.0f;
    #pragma unroll
    for (int c = 0; c < CC; ++c) sum += __expf(hrow[c] - mx);
    const float lse = mx + __logf(sum);

    if (lane < CC) {
        float v = hrow[0];
        #pragma unroll
        for (int c = 1; c < CC; ++c) v = (lane == c) ? hrow[c] : v;
        out[b * CC + lane] = v - lse;
    }
}

extern "C" void kernel_launch(void* const* d_in, const int* in_sizes, int n_in,
                              void* d_out, int out_size, void* d_ws, size_t ws_size,
                              hipStream_t stream)
{
    const float* x  = (const float*)d_in[0];   // [32,128]
    const float* mu = (const float*)d_in[1];   // [10,128]
    const float* U  = (const float*)d_in[2];   // [128,512]
    const float* V  = (const float*)d_in[3];   // [128,512]
    float* out = (float*)d_out;                // [32,10]
    float* fac = (float*)d_ws;                 // [42,512] scratch (86 KB)

    dim3 gridA(BB + CC, KSPLIT);               // 42 x 4 = 168 blocks
    fac_kernel<<<gridA, KCH, 0, stream>>>(x, mu, U, V, fac);
    h_softmax_kernel<<<BB, 64, 0, stream>>>(fac, out);
}